// Round 13
// baseline (307.560 us; speedup 1.0000x reference)
//
#include <hip/hip_runtime.h>
#include <cstdint>

// Problem constants
#define B_  4
#define T_  2048
#define D_  1024
#define H_  16
#define DH_ 64
#define R_  8
#define M_  (B_*T_)          // 8192
#define LORA_SCALE 4.0f

typedef __attribute__((ext_vector_type(8))) short    bf16x8;
typedef __attribute__((ext_vector_type(4))) short    bf16x4;
typedef __attribute__((ext_vector_type(4))) float    f32x4;
typedef __attribute__((ext_vector_type(4))) uint32_t u32x4;

__device__ inline uint16_t f2b(float f) {             // fp32 -> bf16 RNE
    uint32_t x = __float_as_uint(f);
    return (uint16_t)((x + 0x7fffu + ((x >> 16) & 1u)) >> 16);
}
__device__ inline float b2f(uint16_t u) { return __uint_as_float(((uint32_t)u) << 16); }

// packed f32x2 -> bf16x2 (no builtin on gfx950; pure VOP3 asm, schedulable)
__device__ __forceinline__ uint32_t cvtpk(float lo, float hi) {
    uint32_t r;
    asm("v_cvt_pk_bf16_f32 %0, %1, %2" : "=v"(r) : "v"(lo), "v"(hi));
    return r;
}
__device__ __forceinline__ float max3f(float a, float b, float c) {
    float r;
    asm("v_max3_f32 %0, %1, %2, %3" : "=v"(r) : "v"(a), "v"(b), "v"(c));
    return r;
}

__device__ __forceinline__ void gld_lds16(const uint16_t* g, uint16_t* l) {
    __builtin_amdgcn_global_load_lds(
        (const __attribute__((address_space(1))) void*)g,
        (__attribute__((address_space(3))) void*)l, 16, 0, 0);
}

// ---------------------------------------------------------------------------
// K1: cast query fp32 -> bf16   (8 elems/thread)
// ---------------------------------------------------------------------------
__global__ void cast_x_kernel(const float* __restrict__ x, uint16_t* __restrict__ out) {
    int g = blockIdx.x * 256 + threadIdx.x;
    const float4* xv = (const float4*)x;
    float4 a = xv[2 * g], b = xv[2 * g + 1];
    union { u32x4 v; uint16_t s[8]; } u;
    u.s[0] = f2b(a.x); u.s[1] = f2b(a.y); u.s[2] = f2b(a.z); u.s[3] = f2b(a.w);
    u.s[4] = f2b(b.x); u.s[5] = f2b(b.y); u.s[6] = f2b(b.z); u.s[7] = f2b(b.w);
    ((u32x4*)out)[g] = u.v;
}

// ---------------------------------------------------------------------------
// K2: build transposed bf16 weights Wt[n][k]; fold LoRA into wq/wv.
// ---------------------------------------------------------------------------
__global__ void make_wt_kernel(const float* __restrict__ wq, const float* __restrict__ wk,
                               const float* __restrict__ wv, const float* __restrict__ wo,
                               const float* __restrict__ Aq, const float* __restrict__ Bq,
                               const float* __restrict__ Av, const float* __restrict__ Bv,
                               uint16_t* __restrict__ Wt) {
    __shared__ float tile[64][65];
    int mat = blockIdx.z;
    int n0 = blockIdx.x * 64, k0 = blockIdx.y * 64;
    const float* W  = (mat == 0) ? wq : (mat == 1) ? wk : (mat == 2) ? wv : wo;
    const float* Ap = (mat == 0) ? Aq : (mat == 2) ? Av : nullptr;
    const float* Bp = (mat == 0) ? Bq : (mat == 2) ? Bv : nullptr;
    int t = threadIdx.x;
    int r = t >> 2, c0 = (t & 3) * 16;
    int k = k0 + r;
    #pragma unroll
    for (int j = 0; j < 16; j++) {
        int n = n0 + c0 + j;
        float v = W[(size_t)k * D_ + n];
        if (Ap) {
            float acc = 0.f;
            #pragma unroll
            for (int rr = 0; rr < R_; rr++) acc += Ap[k * R_ + rr] * Bp[rr * D_ + n];
            v += LORA_SCALE * acc;
        }
        tile[r][c0 + j] = v;
    }
    __syncthreads();
    int nl = t >> 2, ks = (t & 3) * 16;
    union { uint16_t s[16]; u32x4 v[2]; } uo;
    #pragma unroll
    for (int j = 0; j < 16; j++) uo.s[j] = f2b(tile[ks + j][nl]);
    uint16_t* dst = Wt + (size_t)mat * D_ * D_ + (size_t)(n0 + nl) * D_ + k0 + ks;
    *(u32x4*)&dst[0] = uo.v[0];
    *(u32x4*)&dst[8] = uo.v[1];
}

// ---------------------------------------------------------------------------
// K3/K7: C = A(MxK bf16, row-major) @ Bt(NxK bf16, row-major)^T
// T1 XCD-aware block swizzle: consecutive dispatch ids round-robin across the
// 8 XCDs; remapping wgid=(orig&7)*cpx+(orig>>3) gives each XCD a CONTIGUOUS
// chunk of row-panels, so its 4MB L2 holds 8 A-panels (2MB) instead of
// streaming the whole A matrix.  Bijective: nwg (1536 / 512) % 8 == 0.
// ---------------------------------------------------------------------------
template <bool OUT_F32>
__global__ __launch_bounds__(256)
void gemm_bt_kernel(const uint16_t* __restrict__ A, const uint16_t* __restrict__ Bt,
                    uint16_t* __restrict__ Cb, float* __restrict__ Cf,
                    int Mdim, int Ndim, int Kdim) {
    __shared__ uint16_t At[128 * 32];
    __shared__ uint16_t Bs[128 * 32];
    int tid = threadIdx.x;
    int wave = tid >> 6, lane = tid & 63, quad = lane >> 4, l15 = lane & 15;
    int nwgx = gridDim.x;
    int orig = blockIdx.y * nwgx + blockIdx.x;
    int cpx  = (nwgx * gridDim.y) >> 3;
    int wgid = (orig & 7) * cpx + (orig >> 3);
    int rowBase = (wgid / nwgx) * 128, colBase = (wgid % nwgx) * 128;
    int wRow = (wave >> 1) * 64, wCol = (wave & 1) * 64;
    int srow0 = tid >> 2, sseg0 = (tid & 3) * 8;
    int srow1 = (tid + 256) >> 2;
    f32x4 acc[4][4] = {};
    for (int kb = 0; kb < Kdim; kb += 32) {
        gld_lds16(&A [(size_t)(rowBase + srow0) * Kdim + kb + sseg0], &At[srow0 * 32 + sseg0]);
        gld_lds16(&A [(size_t)(rowBase + srow1) * Kdim + kb + sseg0], &At[srow1 * 32 + sseg0]);
        gld_lds16(&Bt[(size_t)(colBase + srow0) * Kdim + kb + sseg0], &Bs[srow0 * 32 + sseg0]);
        gld_lds16(&Bt[(size_t)(colBase + srow1) * Kdim + kb + sseg0], &Bs[srow1 * 32 + sseg0]);
        __syncthreads();
        bf16x8 af[4], bfr[4];
        #pragma unroll
        for (int m = 0; m < 4; m++) af[m]  = *(const bf16x8*)&At[(wRow + m * 16 + l15) * 32 + quad * 8];
        #pragma unroll
        for (int n = 0; n < 4; n++) bfr[n] = *(const bf16x8*)&Bs[(wCol + n * 16 + l15) * 32 + quad * 8];
        #pragma unroll
        for (int m = 0; m < 4; m++)
            #pragma unroll
            for (int n = 0; n < 4; n++)
                acc[m][n] = __builtin_amdgcn_mfma_f32_16x16x32_bf16(af[m], bfr[n], acc[m][n], 0, 0, 0);
        __syncthreads();
    }
    #pragma unroll
    for (int m = 0; m < 4; m++) {
        int row = rowBase + wRow + m * 16 + quad * 4;
        #pragma unroll
        for (int n = 0; n < 4; n++) {
            int col = colBase + wCol + n * 16 + l15;
            #pragma unroll
            for (int r = 0; r < 4; r++) {
                float v = acc[m][n][r];
                if (OUT_F32) Cf[(size_t)(row + r) * Ndim + col] = v;
                else         Cb[(size_t)(row + r) * Ndim + col] = f2b(v);
            }
        }
    }
}

// ---------------------------------------------------------------------------
// K4: RoPE on q,k; reshape (B,T,3D) -> (B,H,T,dh).
// Qr: linear (B,H,T,dh), PRE-SCALED by 1/sqrt(dh)*log2(e).
// Kr: SWIZZLED within each row: 16B chunk c of row t stored at chunk c^(t&7).
// __sincosf: hardware v_sin/v_cos path, one range reduction (th <= 2047 rad;
// trig error ~2e-4 << bf16 rounding).
// ---------------------------------------------------------------------------
__global__ void rope_kernel(const uint16_t* __restrict__ qkv,
                            uint16_t* __restrict__ Qr, uint16_t* __restrict__ Kr) {
    int g = blockIdx.x * 256 + threadIdx.x;
    int i  = g & 31;
    int t  = (g >> 5) & (T_ - 1);
    int bh = g >> 16;
    int h = bh & 15, b = bh >> 4;
    size_t rowoff = ((size_t)(b * T_ + t)) * 3072 + h * 64 + 2 * i;
    uint32_t qp = *(const uint32_t*)&qkv[rowoff];
    uint32_t kp = *(const uint32_t*)&qkv[rowoff + 1024];
    float qe = b2f((uint16_t)qp), qo = b2f((uint16_t)(qp >> 16));
    float ke = b2f((uint16_t)kp), ko = b2f((uint16_t)(kp >> 16));
    float inv = exp2f(-(float)i * (13.2877123795494f / 32.f));
    float th = (float)t * inv;
    float s, c;
    __sincosf(th, &s, &c);
    const float SC = 0.125f * 1.44269504089f;   // 1/sqrt(64) * log2(e), folded into Q
    uint32_t qw = (uint32_t)f2b((qe * c - qo * s) * SC)
                | ((uint32_t)f2b((qe * s + qo * c) * SC) << 16);
    uint32_t kw = (uint32_t)f2b(ke * c - ko * s) | ((uint32_t)f2b(ke * s + ko * c) << 16);
    size_t o = ((size_t)bh * T_ + t) * 64 + 2 * i;
    *(uint32_t*)&Qr[o] = qw;
    int d = 2 * i;
    size_t kidx = ((size_t)bh * T_ + t) * 64 + ((((d >> 3) ^ (t & 7)) << 3) | (d & 7));
    *(uint32_t*)&Kr[kidx] = kw;
}

// ---------------------------------------------------------------------------
// K5: V -> Vt via LDS tile transpose.  64-t tiles so a 64-kpos chunk is
// CONTIGUOUS 4096 elems in global (verbatim DMA in attn).  Within each
// (64 d x 64 t) tile, 16B t-chunk c of d-row stored at c^(d&7):
// vidx = bh*64*T + (t>>6)*4096 + d*64 + phys*8.
// ---------------------------------------------------------------------------
__global__ void vtrans_kernel(const uint16_t* __restrict__ qkv, uint16_t* __restrict__ Vt) {
    __shared__ uint16_t tile[32][72];
    int bh = blockIdx.y, t0 = blockIdx.x * 32;
    int b = bh >> 4, h = bh & 15;
    int tid = threadIdx.x;
    int r = tid >> 3, c8 = (tid & 7) * 8;
    *(u32x4*)&tile[r][c8] =
        *(const u32x4*)&qkv[((size_t)(b * T_ + t0 + r)) * 3072 + 2048 + h * 64 + c8];
    __syncthreads();
    int d = tid >> 2, t8 = (tid & 3) * 8;
    union { uint16_t s[8]; u32x4 v; } uu;
    #pragma unroll
    for (int j = 0; j < 8; j++) uu.s[j] = tile[t8 + j][d];
    int tt = t0 + t8;
    int c  = (tt & 63) >> 3;
    int phys = (c ^ (d & 7)) & 7;
    size_t vidx = (size_t)bh * 64 * T_ + (size_t)(tt >> 6) * 4096 + d * 64 + phys * 8;
    *(u32x4*)&Vt[vidx] = uu.v;
}

// ---------------------------------------------------------------------------
// K6: causal flash attention -- ROUND-4 VERIFIED STRUCTURE (unchanged).
// chunk=64 kpos, single-buffered verbatim DMA, swizzles baked into Kr/Vt.
// LDS 25.6KB -> 6 blocks/CU; grid 2048 heavy-first; direct reg epilogue.
// Retired experiments (do NOT revisit): double-buffer prefetch (r7/r8, data
// races both with and without explicit vmcnt drains), BK=64 gemm staging
// (r10/r11, nondeterministic), launch fusions (r11/r12, NaN with two
// different gemm bodies while unfused versions pass).
// ---------------------------------------------------------------------------
#define PSTR 72

__device__ __forceinline__ f32x4 mfma16(bf16x8 a, bf16x8 b, f32x4 c) {
    return __builtin_amdgcn_mfma_f32_16x16x32_bf16(a, b, c, 0, 0, 0);
}

template <bool MASKED>
__device__ __forceinline__ void attn_chunk_sw(
    const uint16_t* __restrict__ Kst, const uint16_t* __restrict__ Vst,
    uint16_t* __restrict__ Pw, int nact, int base_kmq,
    bf16x8 aQ0, bf16x8 aQ1, int l15, int quad,
    f32x4 (&Oacc)[4], float& mrow, float& lrow)
{
    int lx = l15 & 7;
    f32x4 sacc[4];
    if (MASKED) {                               // defined values on skipped tiles
        #pragma unroll
        for (int n = 0; n < 4; n++) sacc[n] = f32x4{0.f, 0.f, 0.f, 0.f};
    }
    #pragma unroll
    for (int n = 0; n < 4; n++) {
        if (MASKED && n >= nact) continue;
        int rowK = (n * 16 + l15) * 64;
        bf16x8 kv0 = *(const bf16x8*)&Kst[rowK + ((quad ^ lx) << 3)];
        bf16x8 kv1 = *(const bf16x8*)&Kst[rowK + (((quad + 4) ^ lx) << 3)];
        f32x4 s = {};
        s = mfma16(kv0, aQ0, s);
        s = mfma16(kv1, aQ1, s);
        sacc[n] = s;
    }
    // scores already scaled by 1/sqrt(dh)*log2e (folded into Q at rope time)
    float mx = -1e30f;
    #pragma unroll
    for (int n = 0; n < 4; n++) {
        if (MASKED && n >= nact) continue;
        if (MASKED) {
            #pragma unroll
            for (int r = 0; r < 4; r++) {
                int kmq = base_kmq + n * 16 + quad * 4 + r;   // kpos - q
                if (kmq > 0) sacc[n][r] = -1e30f;
            }
        }
        float t = max3f(sacc[n][0], sacc[n][1], sacc[n][2]);
        mx = max3f(mx, t, sacc[n][3]);
    }
    mx = fmaxf(mx, __shfl_xor(mx, 16, 64));
    mx = fmaxf(mx, __shfl_xor(mx, 32, 64));
    // defer-max: only rescale when the chunk max meaningfully exceeds the
    // running max (wave-uniform branch).  P values bounded by exp2(8)=256.
    if (!__all(mx <= mrow + 8.f)) {
        float mnew = fmaxf(mrow, mx);
        float alpha = exp2f(mrow - mnew);
        #pragma unroll
        for (int m = 0; m < 4; m++)
            #pragma unroll
            for (int r = 0; r < 4; r++) Oacc[m][r] *= alpha;
        lrow *= alpha;
        mrow = mnew;
    }
    float sum = 0.f;
    #pragma unroll
    for (int n = 0; n < 4; n++) {
        if (MASKED && n >= nact) continue;
        #pragma unroll
        for (int r = 0; r < 4; r++) {
            float e = exp2f(sacc[n][r] - mrow);
            sacc[n][r] = e;
            sum += e;
        }
    }
    sum += __shfl_xor(sum, 16, 64);
    sum += __shfl_xor(sum, 32, 64);
    lrow += sum;
    // P^T -> own LDS slab (wave-private, no barrier needed); packed converts
    #pragma unroll
    for (int n = 0; n < 4; n++) {
        if (MASKED && n >= nact) continue;
        uint2 pk;
        pk.x = cvtpk(sacc[n][0], sacc[n][1]);
        pk.y = cvtpk(sacc[n][2], sacc[n][3]);
        *(uint2*)&Pw[l15 * PSTR + n * 16 + quad * 4] = pk;
    }
    if (MASKED && (nact & 1)) {                 // zero odd tail tile for b128 reads
        uint2 z; z.x = 0u; z.y = 0u;
        *(uint2*)&Pw[l15 * PSTR + nact * 16 + quad * 4] = z;
    }
    int ssact = MASKED ? ((nact + 1) >> 1) : 2;
    #pragma unroll
    for (int ss = 0; ss < 2; ss++) {
        if (MASKED && ss >= ssact) continue;
        bf16x8 bP = *(const bf16x8*)&Pw[l15 * PSTR + ss * 32 + quad * 8];
        int cl = ss * 4 + quad;
        int phys = (cl ^ lx) & 7;
        #pragma unroll
        for (int m = 0; m < 4; m++) {
            bf16x8 aV = *(const bf16x8*)&Vst[(m * 16 + l15) * 64 + (phys << 3)];
            Oacc[m] = mfma16(aV, bP, Oacc[m]);
        }
    }
}

__global__ __launch_bounds__(256, 6)
void attn_kernel(const uint16_t* __restrict__ Qr, const uint16_t* __restrict__ Kr,
                 const uint16_t* __restrict__ Vt, uint16_t* __restrict__ Obuf) {
    __shared__ uint16_t KLDS[64 * 64];          // 8192 B, verbatim swizzled tile
    __shared__ uint16_t VLDS[64 * 64];          // 8192 B, verbatim swizzled tile
    __shared__ uint16_t Pl[4][16 * PSTR];       // 9216 B, wave-private slabs
    // XCD swizzle: 8 bh resident per XCD (K/V L2-local); heavy q-tiles first.
    int id  = blockIdx.x;
    int xcd = id & 7, grp = id >> 3;
    int bh  = xcd * 8 + (grp & 7);
    int qt  = 31 - (grp >> 3);                  // 31..0, heavy first
    int b = bh >> 4, h = bh & 15;
    int tid = threadIdx.x, wave = tid >> 6, lane = tid & 63, quad = lane >> 4, l15 = lane & 15;
    const uint16_t* Qbase = Qr + (size_t)bh * T_ * 64;
    const uint16_t* Kbase = Kr + (size_t)bh * T_ * 64;
    const uint16_t* Vbase = Vt + (size_t)bh * 64 * T_;
    uint16_t* Pw = &Pl[wave][0];
    int q0w = qt * 64 + wave * 16;
    bf16x8 aQ0 = *(const bf16x8*)&Qbase[(size_t)(q0w + l15) * 64 + quad * 8];
    bf16x8 aQ1 = *(const bf16x8*)&Qbase[(size_t)(q0w + l15) * 64 + 32 + quad * 8];
    f32x4 Oacc[4] = {};
    float mrow = -1e30f, lrow = 0.f;
    int nch = qt + 1;                           // 64-kpos chunks, uniform across waves
    int klim = q0w + 15;
    int idx0 = tid, idx1 = tid + 256;
    for (int c = 0; c < nch; c++) {
        int k0 = c * 64;
        __syncthreads();                        // (a) all waves done with prev K/V LDS
        const uint16_t* gK = Kbase + (size_t)k0 * 64;       // contiguous swizzled tile
        const uint16_t* gV = Vbase + (size_t)(k0 >> 6) * 4096;
        gld_lds16(gK + idx0 * 8, &KLDS[idx0 * 8]);
        gld_lds16(gK + idx1 * 8, &KLDS[idx1 * 8]);
        gld_lds16(gV + idx0 * 8, &VLDS[idx0 * 8]);
        gld_lds16(gV + idx1 * 8, &VLDS[idx1 * 8]);
        __syncthreads();                        // (b) DMA drained + visible
        if (c == nch - 1) {
            int nact = ((klim - k0) >> 4) + 1;  // causal tail: wave w -> w+1 tiles
            attn_chunk_sw<true>(KLDS, VLDS, Pw, nact, k0 - q0w - l15,
                                aQ0, aQ1, l15, quad, Oacc, mrow, lrow);
        } else {
            attn_chunk_sw<false>(KLDS, VLDS, Pw, 4, 0,
                                 aQ0, aQ1, l15, quad, Oacc, mrow, lrow);
        }
    }
    // epilogue: direct register -> global stores.  Lane (quad,l15) holds
    // O[q=q0w+l15][dh=m*16+quad*4+r]; 4 quads give 32B-contiguous segments.
    float invl = 1.0f / lrow;
    size_t obase = ((size_t)(b * T_ + q0w + l15)) * D_ + h * 64;
    #pragma unroll
    for (int m = 0; m < 4; m++) {
        uint2 ob;
        ob.x = cvtpk(Oacc[m][0] * invl, Oacc[m][1] * invl);
        ob.y = cvtpk(Oacc[m][2] * invl, Oacc[m][3] * invl);
        *(uint2*)&Obuf[obase + m * 16 + quad * 4] = ob;
    }
}

// ---------------------------------------------------------------------------
extern "C" void kernel_launch(void* const* d_in, const int* in_sizes, int n_in,
                              void* d_out, int out_size, void* d_ws, size_t ws_size,
                              hipStream_t stream) {
    const float* query = (const float*)d_in[0];
    const float* wq = (const float*)d_in[1];
    const float* wk = (const float*)d_in[2];
    const float* wv = (const float*)d_in[3];
    const float* wo = (const float*)d_in[4];
    const float* Aq = (const float*)d_in[5];
    const float* Bq = (const float*)d_in[6];
    const float* Av = (const float*)d_in[7];
    const float* Bv = (const float*)d_in[8];
    float* out = (float*)d_out;

    const size_t MB = 1ull << 20;
    if (ws_size < 120 * MB) return;
    char* ws = (char*)d_ws;
    uint16_t* Xbf = (uint16_t*)(ws);                   // 16 MB
    uint16_t* Wt  = (uint16_t*)(ws + 16 * MB);         //  8 MB
    uint16_t* qkv = (uint16_t*)(ws + 24 * MB);         // 48 MB
    uint16_t* Qr  = (uint16_t*)(ws + 72 * MB);         // 16 MB (pre-scaled)
    uint16_t* Kr  = (uint16_t*)(ws + 88 * MB);         // 16 MB (row-swizzled)
    uint16_t* Vt  = (uint16_t*)(ws + 104 * MB);        // 16 MB (64-t tile-swizzled)
    uint16_t* Obuf = qkv;                              // reuse (dead after rope/vtrans)

    cast_x_kernel<<<4096, 256, 0, stream>>>(query, Xbf);
    make_wt_kernel<<<dim3(16, 16, 4), 256, 0, stream>>>(wq, wk, wv, wo, Aq, Bq, Av, Bv, Wt);
    gemm_bt_kernel<false><<<dim3(3072 / 128, M_ / 128), 256, 0, stream>>>(
        Xbf, Wt, qkv, nullptr, M_, 3072, D_);
    rope_kernel<<<16384, 256, 0, stream>>>(qkv, Qr, Kr);
    vtrans_kernel<<<dim3(T_ / 32, B_ * H_), 256, 0, stream>>>(qkv, Vt);
    attn_kernel<<<2048, 256, 0, stream>>>(Qr, Kr, Vt, Obuf);
    gemm_bt_kernel<true><<<dim3(D_ / 128, M_ / 128), 256, 0, stream>>>(
        Obuf, Wt + 3ull * D_ * D_, nullptr, out, M_, D_, D_);
}

// Round 14
// 300.444 us; speedup vs baseline: 1.0237x; 1.0237x over previous
//
#include <hip/hip_runtime.h>
#include <cstdint>

// Problem constants
#define B_  4
#define T_  2048
#define D_  1024
#define H_  16
#define DH_ 64
#define R_  8
#define M_  (B_*T_)          // 8192
#define LORA_SCALE 4.0f

typedef __attribute__((ext_vector_type(8))) short    bf16x8;
typedef __attribute__((ext_vector_type(4))) short    bf16x4;
typedef __attribute__((ext_vector_type(4))) float    f32x4;
typedef __attribute__((ext_vector_type(4))) uint32_t u32x4;

__device__ inline uint16_t f2b(float f) {             // fp32 -> bf16 RNE
    uint32_t x = __float_as_uint(f);
    return (uint16_t)((x + 0x7fffu + ((x >> 16) & 1u)) >> 16);
}
__device__ inline float b2f(uint16_t u) { return __uint_as_float(((uint32_t)u) << 16); }

// packed f32x2 -> bf16x2 (no builtin on gfx950; pure VOP3 asm, schedulable)
__device__ __forceinline__ uint32_t cvtpk(float lo, float hi) {
    uint32_t r;
    asm("v_cvt_pk_bf16_f32 %0, %1, %2" : "=v"(r) : "v"(lo), "v"(hi));
    return r;
}
__device__ __forceinline__ float max3f(float a, float b, float c) {
    float r;
    asm("v_max3_f32 %0, %1, %2, %3" : "=v"(r) : "v"(a), "v"(b), "v"(c));
    return r;
}

__device__ __forceinline__ void gld_lds16(const uint16_t* g, uint16_t* l) {
    __builtin_amdgcn_global_load_lds(
        (const __attribute__((address_space(1))) void*)g,
        (__attribute__((address_space(3))) void*)l, 16, 0, 0);
}

// ---------------------------------------------------------------------------
// K1: cast query fp32 -> bf16   (8 elems/thread)
// ---------------------------------------------------------------------------
__global__ void cast_x_kernel(const float* __restrict__ x, uint16_t* __restrict__ out) {
    int g = blockIdx.x * 256 + threadIdx.x;
    const float4* xv = (const float4*)x;
    float4 a = xv[2 * g], b = xv[2 * g + 1];
    union { u32x4 v; uint16_t s[8]; } u;
    u.s[0] = f2b(a.x); u.s[1] = f2b(a.y); u.s[2] = f2b(a.z); u.s[3] = f2b(a.w);
    u.s[4] = f2b(b.x); u.s[5] = f2b(b.y); u.s[6] = f2b(b.z); u.s[7] = f2b(b.w);
    ((u32x4*)out)[g] = u.v;
}

// ---------------------------------------------------------------------------
// K2: build transposed bf16 weights Wt[n][k]; fold LoRA into wq/wv.
// ---------------------------------------------------------------------------
__global__ void make_wt_kernel(const float* __restrict__ wq, const float* __restrict__ wk,
                               const float* __restrict__ wv, const float* __restrict__ wo,
                               const float* __restrict__ Aq, const float* __restrict__ Bq,
                               const float* __restrict__ Av, const float* __restrict__ Bv,
                               uint16_t* __restrict__ Wt) {
    __shared__ float tile[64][65];
    int mat = blockIdx.z;
    int n0 = blockIdx.x * 64, k0 = blockIdx.y * 64;
    const float* W  = (mat == 0) ? wq : (mat == 1) ? wk : (mat == 2) ? wv : wo;
    const float* Ap = (mat == 0) ? Aq : (mat == 2) ? Av : nullptr;
    const float* Bp = (mat == 0) ? Bq : (mat == 2) ? Bv : nullptr;
    int t = threadIdx.x;
    int r = t >> 2, c0 = (t & 3) * 16;
    int k = k0 + r;
    #pragma unroll
    for (int j = 0; j < 16; j++) {
        int n = n0 + c0 + j;
        float v = W[(size_t)k * D_ + n];
        if (Ap) {
            float acc = 0.f;
            #pragma unroll
            for (int rr = 0; rr < R_; rr++) acc += Ap[k * R_ + rr] * Bp[rr * D_ + n];
            v += LORA_SCALE * acc;
        }
        tile[r][c0 + j] = v;
    }
    __syncthreads();
    int nl = t >> 2, ks = (t & 3) * 16;
    union { uint16_t s[16]; u32x4 v[2]; } uo;
    #pragma unroll
    for (int j = 0; j < 16; j++) uo.s[j] = f2b(tile[ks + j][nl]);
    uint16_t* dst = Wt + (size_t)mat * D_ * D_ + (size_t)(n0 + nl) * D_ + k0 + ks;
    *(u32x4*)&dst[0] = uo.v[0];
    *(u32x4*)&dst[8] = uo.v[1];
}

// ---------------------------------------------------------------------------
// K3/K7: C = A(MxK bf16, row-major) @ Bt(NxK bf16, row-major)^T
// T1 XCD-aware block swizzle (round-9 verified).  MODE selects the epilogue:
//   MODE 1: f32 row-major store (final projection gemm).
//   MODE 2: fused-RoPE QKV scatter.  q/k columns are rotated IN REGISTERS --
//     the RoPE partner (d^1) lives in the adjacent lane (col = ...+l15), so
//     one __shfl_xor(v,1) fetches it; sincos(t*inv_i) computed per element;
//     writes go directly to Qr (pre-scaled by 1/sqrt(dh)*log2e) and Kr
//     (row-swizzled, identical formula to the old rope kernel).  v columns
//     go to qkv for the vtrans kernel.  Kills the 64MB q/k HBM round-trip
//     and the rope dispatch.  Branches are wave-uniform (16-col runs never
//     straddle the 1024/2048 boundaries); shfl sits under a uniform branch.
//     K-loop, staging and barriers BYTE-IDENTICAL to the verified text.
// ---------------------------------------------------------------------------
template <int MODE>
__global__ __launch_bounds__(256)
void gemm_bt_kernel(const uint16_t* __restrict__ A, const uint16_t* __restrict__ Bt,
                    uint16_t* __restrict__ Cb, float* __restrict__ Cf,
                    uint16_t* __restrict__ Qr, uint16_t* __restrict__ Kr,
                    int Mdim, int Ndim, int Kdim) {
    __shared__ uint16_t At[128 * 32];
    __shared__ uint16_t Bs[128 * 32];
    int tid = threadIdx.x;
    int wave = tid >> 6, lane = tid & 63, quad = lane >> 4, l15 = lane & 15;
    int nwgx = gridDim.x;
    int orig = blockIdx.y * nwgx + blockIdx.x;
    int cpx  = (nwgx * gridDim.y) >> 3;
    int wgid = (orig & 7) * cpx + (orig >> 3);
    int rowBase = (wgid / nwgx) * 128, colBase = (wgid % nwgx) * 128;
    int wRow = (wave >> 1) * 64, wCol = (wave & 1) * 64;
    int srow0 = tid >> 2, sseg0 = (tid & 3) * 8;
    int srow1 = (tid + 256) >> 2;
    f32x4 acc[4][4] = {};
    for (int kb = 0; kb < Kdim; kb += 32) {
        gld_lds16(&A [(size_t)(rowBase + srow0) * Kdim + kb + sseg0], &At[srow0 * 32 + sseg0]);
        gld_lds16(&A [(size_t)(rowBase + srow1) * Kdim + kb + sseg0], &At[srow1 * 32 + sseg0]);
        gld_lds16(&Bt[(size_t)(colBase + srow0) * Kdim + kb + sseg0], &Bs[srow0 * 32 + sseg0]);
        gld_lds16(&Bt[(size_t)(colBase + srow1) * Kdim + kb + sseg0], &Bs[srow1 * 32 + sseg0]);
        __syncthreads();
        bf16x8 af[4], bfr[4];
        #pragma unroll
        for (int m = 0; m < 4; m++) af[m]  = *(const bf16x8*)&At[(wRow + m * 16 + l15) * 32 + quad * 8];
        #pragma unroll
        for (int n = 0; n < 4; n++) bfr[n] = *(const bf16x8*)&Bs[(wCol + n * 16 + l15) * 32 + quad * 8];
        #pragma unroll
        for (int m = 0; m < 4; m++)
            #pragma unroll
            for (int n = 0; n < 4; n++)
                acc[m][n] = __builtin_amdgcn_mfma_f32_16x16x32_bf16(af[m], bfr[n], acc[m][n], 0, 0, 0);
        __syncthreads();
    }
    if (MODE == 1) {
        #pragma unroll
        for (int m = 0; m < 4; m++) {
            int row = rowBase + wRow + m * 16 + quad * 4;
            #pragma unroll
            for (int n = 0; n < 4; n++) {
                int col = colBase + wCol + n * 16 + l15;
                #pragma unroll
                for (int r = 0; r < 4; r++)
                    Cf[(size_t)(row + r) * Ndim + col] = acc[m][n][r];
            }
        }
    } else {
        const float SC = 0.125f * 1.44269504089f;   // 1/sqrt(64)*log2e into Q
        #pragma unroll
        for (int n = 0; n < 4; n++) {
            int cc = colBase + wCol + n * 16 + l15;
            if (cc >= 2048) {                       // ---- v third -> qkv (wave-uniform)
                #pragma unroll
                for (int m = 0; m < 4; m++) {
                    int row = rowBase + wRow + m * 16 + quad * 4;
                    #pragma unroll
                    for (int r = 0; r < 4; r++)
                        Cb[(size_t)(row + r) * Ndim + cc] = f2b(acc[m][n][r]);
                }
            } else {                                // ---- q/k: fused RoPE (wave-uniform)
                int d = cc & 63, i = d >> 1, odd = cc & 1;
                int h = (cc >> 6) & 15;
                bool isq = cc < 1024;               // wave-uniform
                float inv = exp2f(-(float)i * (13.2877123795494f / 32.f));
                uint16_t* __restrict__ Dst = isq ? Qr : Kr;
                #pragma unroll
                for (int m = 0; m < 4; m++) {
                    int row = rowBase + wRow + m * 16 + quad * 4;
                    #pragma unroll
                    for (int r = 0; r < 4; r++) {
                        float v = acc[m][n][r];
                        float p = __shfl_xor(v, 1, 64);   // RoPE partner (d^1) lane
                        int gr = row + r;
                        int t  = gr & (T_ - 1), bb = gr >> 11;
                        float s, c;
                        __sincosf((float)t * inv, &s, &c);
                        float o = v * c + (odd ? p * s : -p * s);
                        if (isq) o *= SC;
                        size_t base = ((size_t)(bb * 16 + h) * T_ + t) * 64;
                        int dd = isq ? d : ((((d >> 3) ^ (t & 7)) << 3) | (d & 7));
                        Dst[base + dd] = f2b(o);
                    }
                }
            }
        }
    }
}

// ---------------------------------------------------------------------------
// K5: V -> Vt via LDS tile transpose.  64-t tiles so a 64-kpos chunk is
// CONTIGUOUS 4096 elems in global (verbatim DMA in attn).  Within each
// (64 d x 64 t) tile, 16B t-chunk c of d-row stored at c^(d&7):
// vidx = bh*64*T + (t>>6)*4096 + d*64 + phys*8.
// ---------------------------------------------------------------------------
__global__ void vtrans_kernel(const uint16_t* __restrict__ qkv, uint16_t* __restrict__ Vt) {
    __shared__ uint16_t tile[32][72];
    int bh = blockIdx.y, t0 = blockIdx.x * 32;
    int b = bh >> 4, h = bh & 15;
    int tid = threadIdx.x;
    int r = tid >> 3, c8 = (tid & 7) * 8;
    *(u32x4*)&tile[r][c8] =
        *(const u32x4*)&qkv[((size_t)(b * T_ + t0 + r)) * 3072 + 2048 + h * 64 + c8];
    __syncthreads();
    int d = tid >> 2, t8 = (tid & 3) * 8;
    union { uint16_t s[8]; u32x4 v; } uu;
    #pragma unroll
    for (int j = 0; j < 8; j++) uu.s[j] = tile[t8 + j][d];
    int tt = t0 + t8;
    int c  = (tt & 63) >> 3;
    int phys = (c ^ (d & 7)) & 7;
    size_t vidx = (size_t)bh * 64 * T_ + (size_t)(tt >> 6) * 4096 + d * 64 + phys * 8;
    *(u32x4*)&Vt[vidx] = uu.v;
}

// ---------------------------------------------------------------------------
// K6: causal flash attention -- ROUND-4 VERIFIED STRUCTURE (unchanged).
// chunk=64 kpos, single-buffered verbatim DMA, swizzles baked into Kr/Vt.
// LDS 25.6KB -> 6 blocks/CU; grid 2048 heavy-first; direct reg epilogue.
// Retired experiments (do NOT revisit): double-buffer prefetch (r7/r8),
// BK=64 gemm staging (r10/r11), launch fusions (r11/r12).
// ---------------------------------------------------------------------------
#define PSTR 72

__device__ __forceinline__ f32x4 mfma16(bf16x8 a, bf16x8 b, f32x4 c) {
    return __builtin_amdgcn_mfma_f32_16x16x32_bf16(a, b, c, 0, 0, 0);
}

template <bool MASKED>
__device__ __forceinline__ void attn_chunk_sw(
    const uint16_t* __restrict__ Kst, const uint16_t* __restrict__ Vst,
    uint16_t* __restrict__ Pw, int nact, int base_kmq,
    bf16x8 aQ0, bf16x8 aQ1, int l15, int quad,
    f32x4 (&Oacc)[4], float& mrow, float& lrow)
{
    int lx = l15 & 7;
    f32x4 sacc[4];
    if (MASKED) {                               // defined values on skipped tiles
        #pragma unroll
        for (int n = 0; n < 4; n++) sacc[n] = f32x4{0.f, 0.f, 0.f, 0.f};
    }
    #pragma unroll
    for (int n = 0; n < 4; n++) {
        if (MASKED && n >= nact) continue;
        int rowK = (n * 16 + l15) * 64;
        bf16x8 kv0 = *(const bf16x8*)&Kst[rowK + ((quad ^ lx) << 3)];
        bf16x8 kv1 = *(const bf16x8*)&Kst[rowK + (((quad + 4) ^ lx) << 3)];
        f32x4 s = {};
        s = mfma16(kv0, aQ0, s);
        s = mfma16(kv1, aQ1, s);
        sacc[n] = s;
    }
    // scores already scaled by 1/sqrt(dh)*log2e (folded into Q in gemm1)
    float mx = -1e30f;
    #pragma unroll
    for (int n = 0; n < 4; n++) {
        if (MASKED && n >= nact) continue;
        if (MASKED) {
            #pragma unroll
            for (int r = 0; r < 4; r++) {
                int kmq = base_kmq + n * 16 + quad * 4 + r;   // kpos - q
                if (kmq > 0) sacc[n][r] = -1e30f;
            }
        }
        float t = max3f(sacc[n][0], sacc[n][1], sacc[n][2]);
        mx = max3f(mx, t, sacc[n][3]);
    }
    mx = fmaxf(mx, __shfl_xor(mx, 16, 64));
    mx = fmaxf(mx, __shfl_xor(mx, 32, 64));
    // defer-max: only rescale when the chunk max meaningfully exceeds the
    // running max (wave-uniform branch).  P values bounded by exp2(8)=256.
    if (!__all(mx <= mrow + 8.f)) {
        float mnew = fmaxf(mrow, mx);
        float alpha = exp2f(mrow - mnew);
        #pragma unroll
        for (int m = 0; m < 4; m++)
            #pragma unroll
            for (int r = 0; r < 4; r++) Oacc[m][r] *= alpha;
        lrow *= alpha;
        mrow = mnew;
    }
    float sum = 0.f;
    #pragma unroll
    for (int n = 0; n < 4; n++) {
        if (MASKED && n >= nact) continue;
        #pragma unroll
        for (int r = 0; r < 4; r++) {
            float e = exp2f(sacc[n][r] - mrow);
            sacc[n][r] = e;
            sum += e;
        }
    }
    sum += __shfl_xor(sum, 16, 64);
    sum += __shfl_xor(sum, 32, 64);
    lrow += sum;
    // P^T -> own LDS slab (wave-private, no barrier needed); packed converts
    #pragma unroll
    for (int n = 0; n < 4; n++) {
        if (MASKED && n >= nact) continue;
        uint2 pk;
        pk.x = cvtpk(sacc[n][0], sacc[n][1]);
        pk.y = cvtpk(sacc[n][2], sacc[n][3]);
        *(uint2*)&Pw[l15 * PSTR + n * 16 + quad * 4] = pk;
    }
    if (MASKED && (nact & 1)) {                 // zero odd tail tile for b128 reads
        uint2 z; z.x = 0u; z.y = 0u;
        *(uint2*)&Pw[l15 * PSTR + nact * 16 + quad * 4] = z;
    }
    int ssact = MASKED ? ((nact + 1) >> 1) : 2;
    #pragma unroll
    for (int ss = 0; ss < 2; ss++) {
        if (MASKED && ss >= ssact) continue;
        bf16x8 bP = *(const bf16x8*)&Pw[l15 * PSTR + ss * 32 + quad * 8];
        int cl = ss * 4 + quad;
        int phys = (cl ^ lx) & 7;
        #pragma unroll
        for (int m = 0; m < 4; m++) {
            bf16x8 aV = *(const bf16x8*)&Vst[(m * 16 + l15) * 64 + (phys << 3)];
            Oacc[m] = mfma16(aV, bP, Oacc[m]);
        }
    }
}

__global__ __launch_bounds__(256, 6)
void attn_kernel(const uint16_t* __restrict__ Qr, const uint16_t* __restrict__ Kr,
                 const uint16_t* __restrict__ Vt, uint16_t* __restrict__ Obuf) {
    __shared__ uint16_t KLDS[64 * 64];          // 8192 B, verbatim swizzled tile
    __shared__ uint16_t VLDS[64 * 64];          // 8192 B, verbatim swizzled tile
    __shared__ uint16_t Pl[4][16 * PSTR];       // 9216 B, wave-private slabs
    // XCD swizzle: 8 bh resident per XCD (K/V L2-local); heavy q-tiles first.
    int id  = blockIdx.x;
    int xcd = id & 7, grp = id >> 3;
    int bh  = xcd * 8 + (grp & 7);
    int qt  = 31 - (grp >> 3);                  // 31..0, heavy first
    int b = bh >> 4, h = bh & 15;
    int tid = threadIdx.x, wave = tid >> 6, lane = tid & 63, quad = lane >> 4, l15 = lane & 15;
    const uint16_t* Qbase = Qr + (size_t)bh * T_ * 64;
    const uint16_t* Kbase = Kr + (size_t)bh * T_ * 64;
    const uint16_t* Vbase = Vt + (size_t)bh * 64 * T_;
    uint16_t* Pw = &Pl[wave][0];
    int q0w = qt * 64 + wave * 16;
    bf16x8 aQ0 = *(const bf16x8*)&Qbase[(size_t)(q0w + l15) * 64 + quad * 8];
    bf16x8 aQ1 = *(const bf16x8*)&Qbase[(size_t)(q0w + l15) * 64 + 32 + quad * 8];
    f32x4 Oacc[4] = {};
    float mrow = -1e30f, lrow = 0.f;
    int nch = qt + 1;                           // 64-kpos chunks, uniform across waves
    int klim = q0w + 15;
    int idx0 = tid, idx1 = tid + 256;
    for (int c = 0; c < nch; c++) {
        int k0 = c * 64;
        __syncthreads();                        // (a) all waves done with prev K/V LDS
        const uint16_t* gK = Kbase + (size_t)k0 * 64;       // contiguous swizzled tile
        const uint16_t* gV = Vbase + (size_t)(k0 >> 6) * 4096;
        gld_lds16(gK + idx0 * 8, &KLDS[idx0 * 8]);
        gld_lds16(gK + idx1 * 8, &KLDS[idx1 * 8]);
        gld_lds16(gV + idx0 * 8, &VLDS[idx0 * 8]);
        gld_lds16(gV + idx1 * 8, &VLDS[idx1 * 8]);
        __syncthreads();                        // (b) DMA drained + visible
        if (c == nch - 1) {
            int nact = ((klim - k0) >> 4) + 1;  // causal tail: wave w -> w+1 tiles
            attn_chunk_sw<true>(KLDS, VLDS, Pw, nact, k0 - q0w - l15,
                                aQ0, aQ1, l15, quad, Oacc, mrow, lrow);
        } else {
            attn_chunk_sw<false>(KLDS, VLDS, Pw, 4, 0,
                                 aQ0, aQ1, l15, quad, Oacc, mrow, lrow);
        }
    }
    // epilogue: direct register -> global stores.  Lane (quad,l15) holds
    // O[q=q0w+l15][dh=m*16+quad*4+r]; 4 quads give 32B-contiguous segments.
    float invl = 1.0f / lrow;
    size_t obase = ((size_t)(b * T_ + q0w + l15)) * D_ + h * 64;
    #pragma unroll
    for (int m = 0; m < 4; m++) {
        uint2 ob;
        ob.x = cvtpk(Oacc[m][0] * invl, Oacc[m][1] * invl);
        ob.y = cvtpk(Oacc[m][2] * invl, Oacc[m][3] * invl);
        *(uint2*)&Obuf[obase + m * 16 + quad * 4] = ob;
    }
}

// ---------------------------------------------------------------------------
extern "C" void kernel_launch(void* const* d_in, const int* in_sizes, int n_in,
                              void* d_out, int out_size, void* d_ws, size_t ws_size,
                              hipStream_t stream) {
    const float* query = (const float*)d_in[0];
    const float* wq = (const float*)d_in[1];
    const float* wk = (const float*)d_in[2];
    const float* wv = (const float*)d_in[3];
    const float* wo = (const float*)d_in[4];
    const float* Aq = (const float*)d_in[5];
    const float* Bq = (const float*)d_in[6];
    const float* Av = (const float*)d_in[7];
    const float* Bv = (const float*)d_in[8];
    float* out = (float*)d_out;

    const size_t MB = 1ull << 20;
    if (ws_size < 120 * MB) return;
    char* ws = (char*)d_ws;
    uint16_t* Xbf = (uint16_t*)(ws);                   // 16 MB
    uint16_t* Wt  = (uint16_t*)(ws + 16 * MB);         //  8 MB
    uint16_t* qkv = (uint16_t*)(ws + 24 * MB);         // 48 MB (only v third live)
    uint16_t* Qr  = (uint16_t*)(ws + 72 * MB);         // 16 MB (pre-scaled, RoPE'd)
    uint16_t* Kr  = (uint16_t*)(ws + 88 * MB);         // 16 MB (row-swizzled, RoPE'd)
    uint16_t* Vt  = (uint16_t*)(ws + 104 * MB);        // 16 MB (64-t tile-swizzled)
    uint16_t* Obuf = qkv;                              // reuse (dead after vtrans)

    cast_x_kernel<<<4096, 256, 0, stream>>>(query, Xbf);
    make_wt_kernel<<<dim3(16, 16, 4), 256, 0, stream>>>(wq, wk, wv, wo, Aq, Bq, Av, Bv, Wt);
    gemm_bt_kernel<2><<<dim3(3072 / 128, M_ / 128), 256, 0, stream>>>(
        Xbf, Wt, qkv, nullptr, Qr, Kr, M_, 3072, D_);
    vtrans_kernel<<<dim3(T_ / 32, B_ * H_), 256, 0, stream>>>(qkv, Vt);
    attn_kernel<<<2048, 256, 0, stream>>>(Qr, Kr, Vt, Obuf);
    gemm_bt_kernel<1><<<dim3(D_ / 128, M_ / 128), 256, 0, stream>>>(
        Obuf, Wt + 3ull * D_ * D_, nullptr, out, nullptr, nullptr, M_, D_, D_);
}